// Round 3
// baseline (369.146 us; speedup 1.0000x reference)
//
#include <hip/hip_runtime.h>

// SudokuLoss, cell-per-thread, mask-gated loads.
// B=65536 puzzles, G=9, C=10. mask = (puzzles==0), density ~10%.
// Unmasked cells contribute NOTHING (CE is mask-weighted; wp = probs*mask),
// so only masked lanes load logits/targets (predicated lanes issue no
// memory transactions) -> ~60% less HBM traffic than dense.
// Block = 256 threads = 3 puzzles (243 active lanes).
// Row/col/box accumulation: LDS atomics (~6 active lanes/wave, collisions rare).

constexpr int kB = 65536;
constexpr int kPuzzPerBlk = 3;
constexpr int kBlocks = (kB + kPuzzPerBlk - 1) / kPuzzPerBlk;  // 21846

__global__ __launch_bounds__(256) void sudoku_main(
    const float* __restrict__ logits,
    const int*   __restrict__ targets,
    const int*   __restrict__ puzzles,
    float*       __restrict__ ws)  // [0,kBlocks): diff2, [kBlocks,2k): ce, [2k,3k): mcnt
{
    // acc[q][g][s]: g 0..8 rows, 9..17 cols, 18..26 boxes; s=0 count, s=1..9 class sums
    __shared__ float acc[kPuzzPerBlk][27][10];
    __shared__ float red[4][3];

    const int tid = threadIdx.x;
    for (int i = tid; i < kPuzzPerBlk * 270; i += 256) ((float*)acc)[i] = 0.f;
    __syncthreads();

    float ce = 0.f, mcnt = 0.f, diff2 = 0.f;

    const int q    = tid / 81;          // local puzzle 0..2 (tid<243)
    const int cell = tid - q * 81;      // 0..80
    const int p    = blockIdx.x * kPuzzPerBlk + q;
    const bool valid = (tid < 243) && (p < kB);

    if (valid) {
        const size_t base = (size_t)p * 81 + cell;
        const int pz = puzzles[base];   // dense, lane-consecutive -> coalesced
        if (pz == 0) {
            const int t = targets[base];                 // scattered, ~10% lanes
            const float* xp = logits + base * 10;        // 40 B, 8B-aligned
            float x[10];
            #pragma unroll
            for (int h = 0; h < 5; ++h) {
                const float2 v = *(const float2*)(xp + 2 * h);
                x[2 * h] = v.x; x[2 * h + 1] = v.y;
            }
            float mx = x[0];
            #pragma unroll
            for (int c = 1; c < 10; ++c) mx = fmaxf(mx, x[c]);
            float e[10], S = 0.f;
            #pragma unroll
            for (int c = 0; c < 10; ++c) { e[c] = __expf(x[c] - mx); S += e[c]; }
            const float inv = 1.f / S;
            const float lse = __logf(S);

            float xt = x[0];
            #pragma unroll
            for (int c = 1; c < 10; ++c) xt = (t == c) ? x[c] : xt;
            ce   += mx + lse - xt;       // -log_softmax(x)[target]
            mcnt += 1.f;

            const int r  = cell / 9;
            const int cj = cell - r * 9;
            const int bx = (r / 3) * 3 + (cj / 3);
            float* rowa = acc[q][r];
            float* cola = acc[q][9 + cj];
            float* boxa = acc[q][18 + bx];
            atomicAdd(&rowa[0], 1.f);
            atomicAdd(&cola[0], 1.f);
            atomicAdd(&boxa[0], 1.f);
            #pragma unroll
            for (int c = 1; c < 10; ++c) {
                const float w = e[c] * inv;
                atomicAdd(&rowa[c], w);
                atomicAdd(&cola[c], w);
                atomicAdd(&boxa[c], w);
            }
        }
    }
    __syncthreads();

    // MSE phase: one thread per (puzzle, group): 81 groups per block
    if (tid < kPuzzPerBlk * 27) {
        const int q2 = tid / 27;
        const int g  = tid - q2 * 27;
        if (blockIdx.x * kPuzzPerBlk + q2 < kB) {
            const float* a = acc[q2][g];
            const float tg = a[0] * (1.f / 9.f);
            #pragma unroll
            for (int c = 1; c < 10; ++c) { const float d = a[c] - tg; diff2 += d * d; }
        }
    }

    // block reduction
    #pragma unroll
    for (int off = 32; off > 0; off >>= 1) {
        diff2 += __shfl_down(diff2, off);
        ce    += __shfl_down(ce, off);
        mcnt  += __shfl_down(mcnt, off);
    }
    const int wave = tid >> 6;
    const int lane = tid & 63;
    if (lane == 0) { red[wave][0] = diff2; red[wave][1] = ce; red[wave][2] = mcnt; }
    __syncthreads();
    if (tid == 0) {
        float d = 0.f, c2 = 0.f, m = 0.f;
        #pragma unroll
        for (int wv = 0; wv < 4; ++wv) { d += red[wv][0]; c2 += red[wv][1]; m += red[wv][2]; }
        const int b = blockIdx.x;
        ws[b]               = d;
        ws[kBlocks + b]     = c2;
        ws[2 * kBlocks + b] = m;
    }
}

__global__ __launch_bounds__(1024) void sudoku_final(
    const float* __restrict__ ws, float* __restrict__ out)
{
    __shared__ float red[16][3];
    float s0 = 0.f, s1 = 0.f, s2 = 0.f;
    for (int i = threadIdx.x; i < kBlocks; i += 1024) {
        s0 += ws[i];
        s1 += ws[kBlocks + i];
        s2 += ws[2 * kBlocks + i];
    }
    #pragma unroll
    for (int off = 32; off > 0; off >>= 1) {
        s0 += __shfl_down(s0, off);
        s1 += __shfl_down(s1, off);
        s2 += __shfl_down(s2, off);
    }
    const int wave = threadIdx.x >> 6;
    if ((threadIdx.x & 63) == 0) { red[wave][0] = s0; red[wave][1] = s1; red[wave][2] = s2; }
    __syncthreads();
    if (threadIdx.x == 0) {
        float d = 0.f, c2 = 0.f, m = 0.f;
        #pragma unroll
        for (int wv = 0; wv < 16; ++wv) { d += red[wv][0]; c2 += red[wv][1]; m += red[wv][2]; }
        const float ce_loss    = c2 / (m + 1e-8f);
        const float constraint = d / ((float)kB * 9.f * 27.f);
        out[0] = ce_loss + 0.1f * constraint;
        out[1] = ce_loss;
        out[2] = constraint;
    }
}

extern "C" void kernel_launch(void* const* d_in, const int* in_sizes, int n_in,
                              void* d_out, int out_size, void* d_ws, size_t ws_size,
                              hipStream_t stream)
{
    const float* logits  = (const float*)d_in[0];
    const int*   targets = (const int*)d_in[1];
    const int*   puzzles = (const int*)d_in[2];
    float* ws  = (float*)d_ws;
    float* out = (float*)d_out;

    sudoku_main<<<kBlocks, 256, 0, stream>>>(logits, targets, puzzles, ws);
    sudoku_final<<<1, 1024, 0, stream>>>(ws, out);
}